// Round 5
// baseline (8740.205 us; speedup 1.0000x reference)
//
#include <hip/hip_runtime.h>

#define NN 512
#define DD 32
#define TT 8192

typedef float v4f __attribute__((ext_vector_type(4)));
typedef float v2f __attribute__((ext_vector_type(2)));
typedef float v16f __attribute__((ext_vector_type(16)));
typedef __attribute__((address_space(3))) float lds_f;

constexpr float F_OMEGA = 10.0f;
constexpr float F_DT = 1e-3f;
constexpr float F_TWO_PI = 6.28318530717958647692f;
constexpr float F_INV_TWO_PI = 0.15915494309189533577f;

// Barrier waiting LDS/SMEM only (lgkmcnt), never vmcnt: output stores stay
// in flight across the per-step sync.
__device__ __forceinline__ void barrier_lgkm() {
    asm volatile("s_waitcnt lgkmcnt(0)\n\ts_barrier" ::: "memory");
}

// Asm-laundered LDS read for the partial-sum exchange.
#define DSR128(dst, addr, off) \
    asm volatile("ds_read_b128 %0, %1 offset:" #off : "=v"(dst) : "v"(addr))

// Scalar (SMEM) loads: x is wave-uniform -> SGPRs, scalar cache broadcasts.
#define SL16(dst, ptr, off) \
    asm volatile("s_load_dwordx16 %0, %1, " #off : "=s"(dst) : "s"(ptr))
#define SL1(dst, ptr) \
    asm volatile("s_load_dword %0, %1, 0x0" : "=s"(dst) : "s"(ptr))

// Packed FP32 (VOP3P), <=1 SGPR source per instr. Bit-identical to the
// scalar pairs they replace.
#define PK_MUL_VS(d, a, b) /* d = a*b */ \
    asm("v_pk_mul_f32 %0, %1, %2" : "=v"(d) : "v"(a), "s"(b))
#define PK_FMA_ACC_VS(d, a, b) /* d = a*b + d */ \
    asm("v_pk_fma_f32 %0, %1, %2, %0" : "+v"(d) : "v"(a), "s"(b))
#define PK_FMA_W(w, m, t) /* w = w*m + t */ \
    asm("v_pk_fma_f32 %0, %0, %1, %2" : "+v"(w) : "v"(m), "v"(t))

// One step of a DPP-based wave64 reduction: x += dpp_move(x).
#define DPP_ADD(x, ctrl, rmask)                                                 \
    {                                                                           \
        int _t = __builtin_amdgcn_update_dpp(0, __float_as_int(x),              \
                                             (ctrl), (rmask), 0xf, true);       \
        (x) += __int_as_float(_t);                                              \
    }

__device__ __forceinline__ float wave_reduce_to_lane63(float x) {
    DPP_ADD(x, 0xB1, 0xf);   // + xor1
    DPP_ADD(x, 0x4E, 0xf);   // + xor2
    DPP_ADD(x, 0x141, 0xf);  // + xor4
    DPP_ADD(x, 0x140, 0xf);  // + xor8
    DPP_ADD(x, 0x142, 0xa);  // row_bcast15
    DPP_ADD(x, 0x143, 0xc);  // row_bcast31
    return x;                // lane 63 = full wave sum
}

// Expand two v16f (SGPR-resident) into 16 v2f pair views (SGPR subregs).
#define MKP(dst, lo, hi)                                                        \
    dst[0]  = __builtin_shufflevector(lo, lo, 0, 1);                            \
    dst[1]  = __builtin_shufflevector(lo, lo, 2, 3);                            \
    dst[2]  = __builtin_shufflevector(lo, lo, 4, 5);                            \
    dst[3]  = __builtin_shufflevector(lo, lo, 6, 7);                            \
    dst[4]  = __builtin_shufflevector(lo, lo, 8, 9);                            \
    dst[5]  = __builtin_shufflevector(lo, lo, 10, 11);                          \
    dst[6]  = __builtin_shufflevector(lo, lo, 12, 13);                          \
    dst[7]  = __builtin_shufflevector(lo, lo, 14, 15);                          \
    dst[8]  = __builtin_shufflevector(hi, hi, 0, 1);                            \
    dst[9]  = __builtin_shufflevector(hi, hi, 2, 3);                            \
    dst[10] = __builtin_shufflevector(hi, hi, 4, 5);                            \
    dst[11] = __builtin_shufflevector(hi, hi, 6, 7);                            \
    dst[12] = __builtin_shufflevector(hi, hi, 8, 9);                            \
    dst[13] = __builtin_shufflevector(hi, hi, 10, 11);                          \
    dst[14] = __builtin_shufflevector(hi, hi, 12, 13);                          \
    dst[15] = __builtin_shufflevector(hi, hi, 14, 15);

__global__ __launch_bounds__(512, 2) void deerskin(
    const float* __restrict__ Xr, const float* __restrict__ Xi,
    const float* __restrict__ Tg,
    const float* __restrict__ W0r, const float* __restrict__ W0i,
    const float* __restrict__ Phi0, const float* __restrict__ Beta0,
    float* __restrict__ outs, float* __restrict__ betas, float* __restrict__ gammas)
{
    // Only remaining LDS: 16-float double-buffered partial array.
    __shared__ __align__(16) float sP[16];

    const int n = threadIdx.x;
    const int lane = n & 63;
    const int wid = n >> 6;

    // W row in registers as v2f[16] per re/im. With twr/twi ELIMINATED
    // (t = g*x is recomputed from SGPR-x post-barrier, fused into the W
    // update), live-across-barrier VGPR pressure is ~160 < 256 — the
    // regalloc has no reason to park W in AGPRs (the R0-R4 hidden cost:
    // ~160 v_accvgpr_read/write per thread per step).
    v2f wr2[16], wi2[16];
    {
        const v2f* wr0 = (const v2f*)(W0r + n * DD);
        const v2f* wi0 = (const v2f*)(W0i + n * DD);
#pragma unroll
        for (int k = 0; k < 16; ++k) { wr2[k] = wr0[k]; wi2[k] = wi0[k]; }
    }
    float phi = Phi0[n];
    float beta = Beta0[n];
    float lt = 0.0f;
    float err = 0.0f;

    // Loop-carried SGPR-resident x(t). Single-buffered: x(t) is live until
    // the post-barrier W update; the x(t+1) prefetch is issued AFTER it
    // (WAR enforced by SSA deps), drained by the next step's tie-wait.
    v16f sxr0, sxr1, sxi0, sxi1;
    float stgt;

    // ---- prologue: issue x(0) scalar loads (drained by the t=0 tie-wait).
    SL16(sxr0, Xr, 0x0); SL16(sxr1, Xr, 0x40);
    SL16(sxi0, Xi, 0x0); SL16(sxi1, Xi, 0x40);
    SL1(stgt, Tg);

    for (int t = 0; t < TT; ++t) {
        // ---- 1. x-independent precompute (beta-dependent arm) ----
        const float gamma = __expf(-0.5f * beta);
        const float dtl = gamma * F_DT;
        lt += dtl;
        const float theta = fmaf(F_OMEGA, lt, phi);
        float rev = theta * F_INV_TWO_PI;
        rev -= floorf(rev);
        const float s = __builtin_amdgcn_sinf(rev);
        const float c = __builtin_amdgcn_cosf(rev);
        const float a_sA = 1.0f - __expf(-2.0f * F_DT * (gamma + 1e-6f));
        const float a_sB = 1.0f - __expf(-F_DT / 0.03f);

        // ---- 2. tie-wait for x(t): s_loads issued late in step t-1 ----
        asm volatile("s_waitcnt lgkmcnt(0)"
            : "+s"(sxr0), "+s"(sxr1), "+s"(sxi0), "+s"(sxi1), "+s"(stgt)
            :: "memory");
        const float tgt = stgt;

        v2f xr_[16], xi_[16];
        MKP(xr_, sxr0, sxr1);
        MKP(xi_, sxi0, sxi1);

        // ---- 3. Z = W @ x: 8 packed accumulator chains, VGPR(W) x SGPR(x),
        // same per-lane accumulation order as R0-R4 ----
        v2f arr0, arr1, aii0, aii1, ari0, ari1, air0, air1;
        PK_MUL_VS(arr0, wr2[0], xr_[0]); PK_MUL_VS(arr1, wr2[1], xr_[1]);
        PK_MUL_VS(aii0, wi2[0], xi_[0]); PK_MUL_VS(aii1, wi2[1], xi_[1]);
        PK_MUL_VS(ari0, wr2[0], xi_[0]); PK_MUL_VS(ari1, wr2[1], xi_[1]);
        PK_MUL_VS(air0, wi2[0], xr_[0]); PK_MUL_VS(air1, wi2[1], xr_[1]);
#pragma unroll
        for (int k = 2; k < 16; k += 2) {
            PK_FMA_ACC_VS(arr0, wr2[k], xr_[k]); PK_FMA_ACC_VS(arr1, wr2[k + 1], xr_[k + 1]);
            PK_FMA_ACC_VS(aii0, wi2[k], xi_[k]); PK_FMA_ACC_VS(aii1, wi2[k + 1], xi_[k + 1]);
            PK_FMA_ACC_VS(ari0, wr2[k], xi_[k]); PK_FMA_ACC_VS(ari1, wr2[k + 1], xi_[k + 1]);
            PK_FMA_ACC_VS(air0, wi2[k], xr_[k]); PK_FMA_ACC_VS(air1, wi2[k + 1], xr_[k + 1]);
        }
        const float hArr = (arr0.x + arr0.y) + (arr1.x + arr1.y);
        const float hAii = (aii0.x + aii0.y) + (aii1.x + aii1.y);
        const float hAri = (ari0.x + ari0.y) + (ari1.x + ari1.y);
        const float hAir = (air0.x + air0.y) + (air1.x + air1.y);
        const float zr = hArr - hAii;
        const float zi = hAri + hAir;

        // Y = |Z| * relu(cos(theta - angle(Z))) == relu(zr*cos + zi*sin)
        const float Y = fmaxf(fmaf(zr, c, zi * s), 0.0f);

        // ---- 4. reduce 512 -> 1: DPP wave sum, 8 partials via LDS ----
        float v = wave_reduce_to_lane63(Y * c);
        if (lane == 63) sP[((t & 1) << 3) + wid] = v;

        // ---- 5. pre-barrier tail (no tw array anymore) ----
        const float inv_t = 1.0f / (fabsf(tgt) + 0.01f);
        const float yy = Y * Y;
        const float g = 0.05f * Y * dtl;
        phi += (2.0f / (float)NN) * (-tgt * s) * dtl;
        phi = phi - F_TWO_PI * floorf(phi * F_INV_TWO_PI);
        gammas[t * NN + n] = gamma;   // gamma from OLD beta, per reference

        // ---- 6. barrier (drains only lane63's sP ds_write) ----
        barrier_lgkm();

        // ---- 7. sP partial read (only per-step LDS reads left) ----
        const unsigned lsp =
            (unsigned)(unsigned long long)(lds_f*)&sP[(t & 1) << 3];
        v4f p0, p1;
        DSR128(p0, lsp, 0); DSR128(p1, lsp, 16);
        asm volatile("s_waitcnt lgkmcnt(0)" : "+v"(p0), "+v"(p1) :: "memory");

        // ---- 8. out + short scalar feedback chain ----
        const float out = ((p0.x + p0.y) + (p0.z + p0.w)) +
                          ((p1.x + p1.y) + (p1.z + p1.w));
        const float raw = fabsf(tgt - out);
        err = 0.99f * err + 0.01f * raw;
        const float rel = err * inv_t;
        const float btg = 3.5f * __expf(-5.0f * rel);
        const float a_s = (btg > beta) ? a_sA : a_sB;
        float bnew = beta + a_s * (btg - beta);
        bnew = fminf(fmaxf(bnew, 0.005f), 5.0f);

        // ---- 9. W = W*m1 + g*x, fused: t = g*x (pk_mul from SGPR-x),
        // w = w*m1 + t (pk_fma). Same values, same order as the old
        // twr/twi path — only the temporary is short-lived now. ----
        const float k = (bnew * yy) * dtl;
        const float m1 = 1.0f - k;
        const v2f m12 = {m1, m1};
        const v2f g2 = {g, g};
#pragma unroll
        for (int q = 0; q < 16; ++q) {
            v2f t0, t1;
            PK_MUL_VS(t0, g2, xr_[q]); PK_FMA_W(wr2[q], m12, t0);
            PK_MUL_VS(t1, g2, xi_[q]); PK_FMA_W(wi2[q], m12, t1);
        }

        // ---- 10. prefetch x(t+1) into the same SGPRs (after the W update:
        // x(t) is dead now; drained by next step's tie-wait) ----
        {
            const int tn = (t + 1 < TT) ? (t + 1) : (TT - 1);
            const float* xrp = Xr + (size_t)tn * DD;
            const float* xip = Xi + (size_t)tn * DD;
            const float* tgp = Tg + tn;
            SL16(sxr0, xrp, 0x0); SL16(sxr1, xrp, 0x40);
            SL16(sxi0, xip, 0x0); SL16(sxi1, xip, 0x40);
            SL1(stgt, tgp);
        }

        // ---- 11. outputs (fire-and-forget; no vmcnt waits anywhere) ----
        betas[t * NN + n] = bnew;
        if (lane == 63) outs[t] = out;
        beta = bnew;
    }
}

extern "C" void kernel_launch(void* const* d_in, const int* in_sizes, int n_in,
                              void* d_out, int out_size, void* d_ws, size_t ws_size,
                              hipStream_t stream) {
    const float* Xr    = (const float*)d_in[0];   // [T, D]
    const float* Xi    = (const float*)d_in[1];   // [T, D]
    const float* Tg    = (const float*)d_in[2];   // [T]
    const float* W0r   = (const float*)d_in[3];   // [N, D]
    const float* W0i   = (const float*)d_in[4];   // [N, D]
    const float* Phi0  = (const float*)d_in[5];   // [N]
    const float* Beta0 = (const float*)d_in[6];   // [N]

    float* outs   = (float*)d_out;                // [T]
    float* betas  = outs + TT;                    // [T, N]
    float* gammas = betas + (size_t)TT * NN;      // [T, N]

    deerskin<<<1, NN, 0, stream>>>(Xr, Xi, Tg, W0r, W0i, Phi0, Beta0,
                                   outs, betas, gammas);
}

// Round 6
// 8239.927 us; speedup vs baseline: 1.0607x; 1.0607x over previous
//
#include <hip/hip_runtime.h>

#define NN 512
#define DD 32
#define TT 8192

typedef float v4f __attribute__((ext_vector_type(4)));
typedef float v2f __attribute__((ext_vector_type(2)));
typedef float v16f __attribute__((ext_vector_type(16)));
typedef __attribute__((address_space(3))) float lds_f;

constexpr float F_OMEGA = 10.0f;
constexpr float F_DT = 1e-3f;
constexpr float F_TWO_PI = 6.28318530717958647692f;
constexpr float F_INV_TWO_PI = 0.15915494309189533577f;

__device__ __forceinline__ void barrier_lgkm() {
    asm volatile("s_waitcnt lgkmcnt(0)\n\ts_barrier" ::: "memory");
}

#define DSR128(dst, addr, off) \
    asm volatile("ds_read_b128 %0, %1 offset:" #off : "=v"(dst) : "v"(addr))

#define SL16(dst, ptr, off) \
    asm volatile("s_load_dwordx16 %0, %1, " #off : "=s"(dst) : "s"(ptr))
#define SL1(dst, ptr) \
    asm volatile("s_load_dword %0, %1, 0x0" : "=s"(dst) : "s"(ptr))

#define DPP_ADD(x, ctrl, rmask)                                                 \
    {                                                                           \
        int _t = __builtin_amdgcn_update_dpp(0, __float_as_int(x),              \
                                             (ctrl), (rmask), 0xf, true);       \
        (x) += __int_as_float(_t);                                              \
    }

__device__ __forceinline__ float wave_reduce_to_lane63(float x) {
    DPP_ADD(x, 0xB1, 0xf);   // + xor1
    DPP_ADD(x, 0x4E, 0xf);   // + xor2
    DPP_ADD(x, 0x141, 0xf);  // + xor4
    DPP_ADD(x, 0x140, 0xf);  // + xor8
    DPP_ADD(x, 0x142, 0xa);  // row_bcast15
    DPP_ADD(x, 0x143, 0xc);  // row_bcast31
    return x;                // lane 63 = full wave sum
}

// Expand two v16f (SGPR-resident) into 16 v2f pair views (SGPR subregs).
#define MKP(dst, lo, hi)                                                        \
    dst[0]  = __builtin_shufflevector(lo, lo, 0, 1);                            \
    dst[1]  = __builtin_shufflevector(lo, lo, 2, 3);                            \
    dst[2]  = __builtin_shufflevector(lo, lo, 4, 5);                            \
    dst[3]  = __builtin_shufflevector(lo, lo, 6, 7);                            \
    dst[4]  = __builtin_shufflevector(lo, lo, 8, 9);                            \
    dst[5]  = __builtin_shufflevector(lo, lo, 10, 11);                          \
    dst[6]  = __builtin_shufflevector(lo, lo, 12, 13);                          \
    dst[7]  = __builtin_shufflevector(lo, lo, 14, 15);                          \
    dst[8]  = __builtin_shufflevector(hi, hi, 0, 1);                            \
    dst[9]  = __builtin_shufflevector(hi, hi, 2, 3);                            \
    dst[10] = __builtin_shufflevector(hi, hi, 4, 5);                            \
    dst[11] = __builtin_shufflevector(hi, hi, 6, 7);                            \
    dst[12] = __builtin_shufflevector(hi, hi, 8, 9);                            \
    dst[13] = __builtin_shufflevector(hi, hi, 10, 11);                          \
    dst[14] = __builtin_shufflevector(hi, hi, 12, 13);                          \
    dst[15] = __builtin_shufflevector(hi, hi, 14, 15);

// x pair operand lists for the asm blobs (16 "s" inputs each).
#define XIN(x) \
    "s"(x[0]), "s"(x[1]), "s"(x[2]), "s"(x[3]), "s"(x[4]), "s"(x[5]), \
    "s"(x[6]), "s"(x[7]), "s"(x[8]), "s"(x[9]), "s"(x[10]), "s"(x[11]), \
    "s"(x[12]), "s"(x[13]), "s"(x[14]), "s"(x[15])

__global__ __launch_bounds__(512, 2) void deerskin(
    const float* __restrict__ Xr, const float* __restrict__ Xi,
    const float* __restrict__ Tg,
    const float* __restrict__ W0r, const float* __restrict__ W0i,
    const float* __restrict__ Phi0, const float* __restrict__ Beta0,
    float* __restrict__ outs, float* __restrict__ betas, float* __restrict__ gammas)
{
    // Only remaining LDS: 16-float double-buffered partial array.
    __shared__ __align__(16) float sP[16];

    const int n = threadIdx.x;
    const int lane = n & 63;
    const int wid = n >> 6;

    // ---- W state PINNED to physical ArchVGPRs v[64:127] ----
    // wr2[k] = v[64+2k:65+2k], wi2[k] = v[96+2k:97+2k], k = 0..15.
    // R0-R5 post-mortem: the register allocator homes W in AGPRs (VGPR_Count
    // =48 << 128 needed) and brackets every "v"-constrained asm op with
    // v_accvgpr_read/write (~190 extra VALU movs/thread/step). Physreg
    // constraints take the decision away from it: the four v16f values are
    // live-range-pinned to v[64:127]; asm bodies reference the pairs
    // directly; the compiler cannot allocate anything else there.
    v16f wrA, wrB, wiA, wiB;
    {
        const v16f* r = (const v16f*)(W0r + n * DD);
        const v16f* i = (const v16f*)(W0i + n * DD);
        v16f t0 = r[0], t1 = r[1], t2 = i[0], t3 = i[1];
        asm volatile("" : "={v[64:79]}"(wrA) : "0"(t0));
        asm volatile("" : "={v[80:95]}"(wrB) : "0"(t1));
        asm volatile("" : "={v[96:111]}"(wiA) : "0"(t2));
        asm volatile("" : "={v[112:127]}"(wiB) : "0"(t3));
    }
    float phi = Phi0[n];
    float beta = Beta0[n];
    float lt = 0.0f;
    float err = 0.0f;

    // Loop-carried SGPR-resident x(t).
    v16f sxr0, sxr1, sxi0, sxi1;
    float stgt;

    // ---- prologue: issue x(0) scalar loads (drained by the t=0 tie-wait).
    SL16(sxr0, Xr, 0x0); SL16(sxr1, Xr, 0x40);
    SL16(sxi0, Xi, 0x0); SL16(sxi1, Xi, 0x40);
    SL1(stgt, Tg);

    for (int t = 0; t < TT; ++t) {
        // ---- 1. x-independent precompute (beta-dependent arm) ----
        const float gamma = __expf(-0.5f * beta);
        const float dtl = gamma * F_DT;
        lt += dtl;
        const float theta = fmaf(F_OMEGA, lt, phi);
        float rev = theta * F_INV_TWO_PI;
        rev -= floorf(rev);
        const float s = __builtin_amdgcn_sinf(rev);
        const float c = __builtin_amdgcn_cosf(rev);
        const float a_sA = 1.0f - __expf(-2.0f * F_DT * (gamma + 1e-6f));
        const float a_sB = 1.0f - __expf(-F_DT / 0.03f);

        // ---- 2. tie-wait for x(t) ----
        asm volatile("s_waitcnt lgkmcnt(0)"
            : "+s"(sxr0), "+s"(sxr1), "+s"(sxi0), "+s"(sxi1), "+s"(stgt)
            :: "memory");
        const float tgt = stgt;

        v2f xr_[16], xi_[16];
        MKP(xr_, sxr0, sxr1);
        MKP(xi_, sxi0, sxi1);

        // ---- 3. Z = W @ x: two blobs, pinned-W pairs referenced directly.
        // Chain order per accumulator identical to R5 -> bit-identical FP.
        v2f arr0, arr1, aii0, aii1, ari0, ari1, air0, air1;
        asm volatile(
            "v_pk_mul_f32 %0, v[64:65], %8\n\t"
            "v_pk_mul_f32 %1, v[66:67], %9\n\t"
            "v_pk_mul_f32 %2, v[96:97], %8\n\t"
            "v_pk_mul_f32 %3, v[98:99], %9\n\t"
            "v_pk_fma_f32 %0, v[68:69], %10, %0\n\t"
            "v_pk_fma_f32 %1, v[70:71], %11, %1\n\t"
            "v_pk_fma_f32 %2, v[100:101], %10, %2\n\t"
            "v_pk_fma_f32 %3, v[102:103], %11, %3\n\t"
            "v_pk_fma_f32 %0, v[72:73], %12, %0\n\t"
            "v_pk_fma_f32 %1, v[74:75], %13, %1\n\t"
            "v_pk_fma_f32 %2, v[104:105], %12, %2\n\t"
            "v_pk_fma_f32 %3, v[106:107], %13, %3\n\t"
            "v_pk_fma_f32 %0, v[76:77], %14, %0\n\t"
            "v_pk_fma_f32 %1, v[78:79], %15, %1\n\t"
            "v_pk_fma_f32 %2, v[108:109], %14, %2\n\t"
            "v_pk_fma_f32 %3, v[110:111], %15, %3\n\t"
            "v_pk_fma_f32 %0, v[80:81], %16, %0\n\t"
            "v_pk_fma_f32 %1, v[82:83], %17, %1\n\t"
            "v_pk_fma_f32 %2, v[112:113], %16, %2\n\t"
            "v_pk_fma_f32 %3, v[114:115], %17, %3\n\t"
            "v_pk_fma_f32 %0, v[84:85], %18, %0\n\t"
            "v_pk_fma_f32 %1, v[86:87], %19, %1\n\t"
            "v_pk_fma_f32 %2, v[116:117], %18, %2\n\t"
            "v_pk_fma_f32 %3, v[118:119], %19, %3\n\t"
            "v_pk_fma_f32 %0, v[88:89], %20, %0\n\t"
            "v_pk_fma_f32 %1, v[90:91], %21, %1\n\t"
            "v_pk_fma_f32 %2, v[120:121], %20, %2\n\t"
            "v_pk_fma_f32 %3, v[122:123], %21, %3\n\t"
            "v_pk_fma_f32 %0, v[92:93], %22, %0\n\t"
            "v_pk_fma_f32 %1, v[94:95], %23, %1\n\t"
            "v_pk_fma_f32 %2, v[124:125], %22, %2\n\t"
            "v_pk_fma_f32 %3, v[126:127], %23, %3"
            : "=&v"(arr0), "=&v"(arr1), "=&v"(air0), "=&v"(air1)
            : "{v[64:79]}"(wrA), "{v[80:95]}"(wrB),
              "{v[96:111]}"(wiA), "{v[112:127]}"(wiB), XIN(xr_));
        asm volatile(
            "v_pk_mul_f32 %0, v[96:97], %8\n\t"
            "v_pk_mul_f32 %1, v[98:99], %9\n\t"
            "v_pk_mul_f32 %2, v[64:65], %8\n\t"
            "v_pk_mul_f32 %3, v[66:67], %9\n\t"
            "v_pk_fma_f32 %0, v[100:101], %10, %0\n\t"
            "v_pk_fma_f32 %1, v[102:103], %11, %1\n\t"
            "v_pk_fma_f32 %2, v[68:69], %10, %2\n\t"
            "v_pk_fma_f32 %3, v[70:71], %11, %3\n\t"
            "v_pk_fma_f32 %0, v[104:105], %12, %0\n\t"
            "v_pk_fma_f32 %1, v[106:107], %13, %1\n\t"
            "v_pk_fma_f32 %2, v[72:73], %12, %2\n\t"
            "v_pk_fma_f32 %3, v[74:75], %13, %3\n\t"
            "v_pk_fma_f32 %0, v[108:109], %14, %0\n\t"
            "v_pk_fma_f32 %1, v[110:111], %15, %1\n\t"
            "v_pk_fma_f32 %2, v[76:77], %14, %2\n\t"
            "v_pk_fma_f32 %3, v[78:79], %15, %3\n\t"
            "v_pk_fma_f32 %0, v[112:113], %16, %0\n\t"
            "v_pk_fma_f32 %1, v[114:115], %17, %1\n\t"
            "v_pk_fma_f32 %2, v[80:81], %16, %2\n\t"
            "v_pk_fma_f32 %3, v[82:83], %17, %3\n\t"
            "v_pk_fma_f32 %0, v[116:117], %18, %0\n\t"
            "v_pk_fma_f32 %1, v[118:119], %19, %1\n\t"
            "v_pk_fma_f32 %2, v[84:85], %18, %2\n\t"
            "v_pk_fma_f32 %3, v[86:87], %19, %3\n\t"
            "v_pk_fma_f32 %0, v[120:121], %20, %0\n\t"
            "v_pk_fma_f32 %1, v[122:123], %21, %1\n\t"
            "v_pk_fma_f32 %2, v[88:89], %20, %2\n\t"
            "v_pk_fma_f32 %3, v[90:91], %21, %3\n\t"
            "v_pk_fma_f32 %0, v[124:125], %22, %0\n\t"
            "v_pk_fma_f32 %1, v[126:127], %23, %1\n\t"
            "v_pk_fma_f32 %2, v[92:93], %22, %2\n\t"
            "v_pk_fma_f32 %3, v[94:95], %23, %3"
            : "=&v"(aii0), "=&v"(aii1), "=&v"(ari0), "=&v"(ari1)
            : "{v[64:79]}"(wrA), "{v[80:95]}"(wrB),
              "{v[96:111]}"(wiA), "{v[112:127]}"(wiB), XIN(xi_));

        const float hArr = (arr0.x + arr0.y) + (arr1.x + arr1.y);
        const float hAii = (aii0.x + aii0.y) + (aii1.x + aii1.y);
        const float hAri = (ari0.x + ari0.y) + (ari1.x + ari1.y);
        const float hAir = (air0.x + air0.y) + (air1.x + air1.y);
        const float zr = hArr - hAii;
        const float zi = hAri + hAir;

        // Y = |Z| * relu(cos(theta - angle(Z))) == relu(zr*cos + zi*sin)
        const float Y = fmaxf(fmaf(zr, c, zi * s), 0.0f);

        // ---- 4. reduce 512 -> 1: DPP wave sum, 8 partials via LDS ----
        float v = wave_reduce_to_lane63(Y * c);
        if (lane == 63) sP[((t & 1) << 3) + wid] = v;

        // ---- 5. pre-barrier tail ----
        const float inv_t = 1.0f / (fabsf(tgt) + 0.01f);
        const float yy = Y * Y;
        const float g = 0.05f * Y * dtl;
        phi += (2.0f / (float)NN) * (-tgt * s) * dtl;
        phi = phi - F_TWO_PI * floorf(phi * F_INV_TWO_PI);
        gammas[t * NN + n] = gamma;   // gamma from OLD beta, per reference

        // ---- 6. barrier (drains only lane63's sP ds_write) ----
        barrier_lgkm();

        // ---- 7. sP partial read ----
        const unsigned lsp =
            (unsigned)(unsigned long long)(lds_f*)&sP[(t & 1) << 3];
        v4f p0, p1;
        DSR128(p0, lsp, 0); DSR128(p1, lsp, 16);
        asm volatile("s_waitcnt lgkmcnt(0)" : "+v"(p0), "+v"(p1) :: "memory");

        // ---- 8. out + short scalar feedback chain ----
        const float out = ((p0.x + p0.y) + (p0.z + p0.w)) +
                          ((p1.x + p1.y) + (p1.z + p1.w));
        const float raw = fabsf(tgt - out);
        err = 0.99f * err + 0.01f * raw;
        const float rel = err * inv_t;
        const float btg = 3.5f * __expf(-5.0f * rel);
        const float a_s = (btg > beta) ? a_sA : a_sB;
        float bnew = beta + a_s * (btg - beta);
        bnew = fminf(fmaxf(bnew, 0.005f), 5.0f);

        // ---- 9. W = W*m1 + g*x on the pinned regs (same mul->fma per pair,
        // same operand roles and order as R5 -> bit-identical) ----
        const float k = (bnew * yy) * dtl;
        const float m1 = 1.0f - k;
        const v2f m12 = {m1, m1};
        const v2f g2 = {g, g};
        asm volatile(
            "v_pk_mul_f32 v[128:129], %2, %4\n\t"
            "v_pk_fma_f32 v[64:65], v[64:65], %3, v[128:129]\n\t"
            "v_pk_mul_f32 v[130:131], %2, %5\n\t"
            "v_pk_fma_f32 v[66:67], v[66:67], %3, v[130:131]\n\t"
            "v_pk_mul_f32 v[128:129], %2, %6\n\t"
            "v_pk_fma_f32 v[68:69], v[68:69], %3, v[128:129]\n\t"
            "v_pk_mul_f32 v[130:131], %2, %7\n\t"
            "v_pk_fma_f32 v[70:71], v[70:71], %3, v[130:131]\n\t"
            "v_pk_mul_f32 v[128:129], %2, %8\n\t"
            "v_pk_fma_f32 v[72:73], v[72:73], %3, v[128:129]\n\t"
            "v_pk_mul_f32 v[130:131], %2, %9\n\t"
            "v_pk_fma_f32 v[74:75], v[74:75], %3, v[130:131]\n\t"
            "v_pk_mul_f32 v[128:129], %2, %10\n\t"
            "v_pk_fma_f32 v[76:77], v[76:77], %3, v[128:129]\n\t"
            "v_pk_mul_f32 v[130:131], %2, %11\n\t"
            "v_pk_fma_f32 v[78:79], v[78:79], %3, v[130:131]\n\t"
            "v_pk_mul_f32 v[128:129], %2, %12\n\t"
            "v_pk_fma_f32 v[80:81], v[80:81], %3, v[128:129]\n\t"
            "v_pk_mul_f32 v[130:131], %2, %13\n\t"
            "v_pk_fma_f32 v[82:83], v[82:83], %3, v[130:131]\n\t"
            "v_pk_mul_f32 v[128:129], %2, %14\n\t"
            "v_pk_fma_f32 v[84:85], v[84:85], %3, v[128:129]\n\t"
            "v_pk_mul_f32 v[130:131], %2, %15\n\t"
            "v_pk_fma_f32 v[86:87], v[86:87], %3, v[130:131]\n\t"
            "v_pk_mul_f32 v[128:129], %2, %16\n\t"
            "v_pk_fma_f32 v[88:89], v[88:89], %3, v[128:129]\n\t"
            "v_pk_mul_f32 v[130:131], %2, %17\n\t"
            "v_pk_fma_f32 v[90:91], v[90:91], %3, v[130:131]\n\t"
            "v_pk_mul_f32 v[128:129], %2, %18\n\t"
            "v_pk_fma_f32 v[92:93], v[92:93], %3, v[128:129]\n\t"
            "v_pk_mul_f32 v[130:131], %2, %19\n\t"
            "v_pk_fma_f32 v[94:95], v[94:95], %3, v[130:131]"
            : "+{v[64:79]}"(wrA), "+{v[80:95]}"(wrB)
            : "v"(g2), "v"(m12), XIN(xr_)
            : "v128", "v129", "v130", "v131");
        asm volatile(
            "v_pk_mul_f32 v[128:129], %2, %4\n\t"
            "v_pk_fma_f32 v[96:97], v[96:97], %3, v[128:129]\n\t"
            "v_pk_mul_f32 v[130:131], %2, %5\n\t"
            "v_pk_fma_f32 v[98:99], v[98:99], %3, v[130:131]\n\t"
            "v_pk_mul_f32 v[128:129], %2, %6\n\t"
            "v_pk_fma_f32 v[100:101], v[100:101], %3, v[128:129]\n\t"
            "v_pk_mul_f32 v[130:131], %2, %7\n\t"
            "v_pk_fma_f32 v[102:103], v[102:103], %3, v[130:131]\n\t"
            "v_pk_mul_f32 v[128:129], %2, %8\n\t"
            "v_pk_fma_f32 v[104:105], v[104:105], %3, v[128:129]\n\t"
            "v_pk_mul_f32 v[130:131], %2, %9\n\t"
            "v_pk_fma_f32 v[106:107], v[106:107], %3, v[130:131]\n\t"
            "v_pk_mul_f32 v[128:129], %2, %10\n\t"
            "v_pk_fma_f32 v[108:109], v[108:109], %3, v[128:129]\n\t"
            "v_pk_mul_f32 v[130:131], %2, %11\n\t"
            "v_pk_fma_f32 v[110:111], v[110:111], %3, v[130:131]\n\t"
            "v_pk_mul_f32 v[128:129], %2, %12\n\t"
            "v_pk_fma_f32 v[112:113], v[112:113], %3, v[128:129]\n\t"
            "v_pk_mul_f32 v[130:131], %2, %13\n\t"
            "v_pk_fma_f32 v[114:115], v[114:115], %3, v[130:131]\n\t"
            "v_pk_mul_f32 v[128:129], %2, %14\n\t"
            "v_pk_fma_f32 v[116:117], v[116:117], %3, v[128:129]\n\t"
            "v_pk_mul_f32 v[130:131], %2, %15\n\t"
            "v_pk_fma_f32 v[118:119], v[118:119], %3, v[130:131]\n\t"
            "v_pk_mul_f32 v[128:129], %2, %16\n\t"
            "v_pk_fma_f32 v[120:121], v[120:121], %3, v[128:129]\n\t"
            "v_pk_mul_f32 v[130:131], %2, %17\n\t"
            "v_pk_fma_f32 v[122:123], v[122:123], %3, v[130:131]\n\t"
            "v_pk_mul_f32 v[128:129], %2, %18\n\t"
            "v_pk_fma_f32 v[124:125], v[124:125], %3, v[128:129]\n\t"
            "v_pk_mul_f32 v[130:131], %2, %19\n\t"
            "v_pk_fma_f32 v[126:127], v[126:127], %3, v[130:131]"
            : "+{v[96:111]}"(wiA), "+{v[112:127]}"(wiB)
            : "v"(g2), "v"(m12), XIN(xi_)
            : "v128", "v129", "v130", "v131");

        // ---- 10. prefetch x(t+1) (x(t) is dead after the W update) ----
        {
            const int tn = (t + 1 < TT) ? (t + 1) : (TT - 1);
            const float* xrp = Xr + (size_t)tn * DD;
            const float* xip = Xi + (size_t)tn * DD;
            const float* tgp = Tg + tn;
            SL16(sxr0, xrp, 0x0); SL16(sxr1, xrp, 0x40);
            SL16(sxi0, xip, 0x0); SL16(sxi1, xip, 0x40);
            SL1(stgt, tgp);
        }

        // ---- 11. outputs (fire-and-forget; no vmcnt waits anywhere) ----
        betas[t * NN + n] = bnew;
        if (lane == 63) outs[t] = out;
        beta = bnew;
    }
}

extern "C" void kernel_launch(void* const* d_in, const int* in_sizes, int n_in,
                              void* d_out, int out_size, void* d_ws, size_t ws_size,
                              hipStream_t stream) {
    const float* Xr    = (const float*)d_in[0];   // [T, D]
    const float* Xi    = (const float*)d_in[1];   // [T, D]
    const float* Tg    = (const float*)d_in[2];   // [T]
    const float* W0r   = (const float*)d_in[3];   // [N, D]
    const float* W0i   = (const float*)d_in[4];   // [N, D]
    const float* Phi0  = (const float*)d_in[5];   // [N]
    const float* Beta0 = (const float*)d_in[6];   // [N]

    float* outs   = (float*)d_out;                // [T]
    float* betas  = outs + TT;                    // [T, N]
    float* gammas = betas + (size_t)TT * NN;      // [T, N]

    deerskin<<<1, NN, 0, stream>>>(Xr, Xi, Tg, W0r, W0i, Phi0, Beta0,
                                   outs, betas, gammas);
}